// Round 1
// baseline (483.335 us; speedup 1.0000x reference)
//
#include <hip/hip_runtime.h>

typedef __bf16 v8bf __attribute__((ext_vector_type(8)));
typedef float  v4f  __attribute__((ext_vector_type(4)));

__device__ inline unsigned pack_bf16x2(float x, float y) {
    unsigned short a = __builtin_bit_cast(unsigned short, (__bf16)x);
    unsigned short b = __builtin_bit_cast(unsigned short, (__bf16)y);
    return (unsigned)a | ((unsigned)b << 16);
}

// ---- counters layout in ws (int indices) ----
// [0..7]  cnt1   [8..15] cnt2   [16..23] cursor1  [24..31] cursor2
// [32..40] gs1   [41..49] gs2   [50..58] tb1      [59..67] tb2

__global__ void pack_weights(const float* __restrict__ W1, const float* __restrict__ W2,
                             const float* __restrict__ W3, const float* __restrict__ T2,
                             const float* __restrict__ T3,
                             __bf16* __restrict__ W3T, __bf16* __restrict__ BT3,
                             __bf16* __restrict__ BT2) {
    int idx = blockIdx.x * 256 + threadIdx.x;
    if (idx < 32768) {
        // W3T[d][c] = W3[c][d], d<128, c<256
        int c = idx & 255, d = idx >> 8;
        W3T[d * 256 + c] = (__bf16)W3[c * 128 + d];
    } else if (idx < 32768 + 262144) {
        // BT3[k][d][c]: c<128 -> T3[k][c][d], else W2[c-128][d]
        int t = idx - 32768;
        int c = t & 255, rest = t >> 8;
        int d = rest & 127, k = rest >> 7;
        float v = (c < 128) ? T3[((k * 128 + c) * 128) + d] : W2[(c - 128) * 128 + d];
        BT3[t] = (__bf16)v;
    } else if (idx < 32768 + 262144 + 196608) {
        // BT2[k][d][c]: c<128 -> T2[k][c][d], else W1[c-128][d]  (c<192)
        int t = idx - (32768 + 262144);
        int c = t % 192, rest = t / 192;
        int d = rest & 127, k = rest >> 7;
        float v = (c < 128) ? T2[((k * 128 + c) * 128) + d] : W1[(c - 128) * 128 + d];
        BT2[t] = (__bf16)v;
    }
}

__global__ void hist_kernel(const int* __restrict__ off1, int n1,
                            const int* __restrict__ off2, int n2, int* __restrict__ ctr) {
    __shared__ int lh[16];
    if (threadIdx.x < 16) lh[threadIdx.x] = 0;
    __syncthreads();
    int total = n1 + n2;
    for (int idx = blockIdx.x * blockDim.x + threadIdx.x; idx < total;
         idx += gridDim.x * blockDim.x) {
        if (idx < n1) atomicAdd(&lh[off1[idx]], 1);
        else          atomicAdd(&lh[8 + off2[idx - n1]], 1);
    }
    __syncthreads();
    if (threadIdx.x < 16) atomicAdd(&ctr[threadIdx.x], lh[threadIdx.x]);
}

__global__ void scan_kernel(int* ctr) {
    if (threadIdx.x == 0 && blockIdx.x == 0) {
        int s = 0, tb = 0;
        for (int g = 0; g < 8; ++g) {
            ctr[32 + g] = s; ctr[16 + g] = s; ctr[50 + g] = tb;
            s += ctr[g]; tb += (ctr[g] + 63) >> 6;
        }
        ctr[32 + 8] = s; ctr[50 + 8] = tb;
        s = 0; tb = 0;
        for (int g = 0; g < 8; ++g) {
            ctr[41 + g] = s; ctr[24 + g] = s; ctr[59 + g] = tb;
            s += ctr[8 + g]; tb += (ctr[8 + g] + 63) >> 6;
        }
        ctr[41 + 8] = s; ctr[59 + 8] = tb;
    }
}

__global__ void scatter_kernel(const int* __restrict__ off1, int n1, int nb1,
                               const int* __restrict__ off2, int n2,
                               int* __restrict__ ctr, int* __restrict__ perm1,
                               int* __restrict__ perm2) {
    __shared__ int lh[8], gb[8];
    const int* off; int n, base; int* cursor; int* perm;
    if ((int)blockIdx.x < nb1) {
        off = off1; n = n1; base = blockIdx.x * 1024; cursor = ctr + 16; perm = perm1;
    } else {
        off = off2; n = n2; base = (blockIdx.x - nb1) * 1024; cursor = ctr + 24; perm = perm2;
    }
    if (threadIdx.x < 8) lh[threadIdx.x] = 0;
    __syncthreads();
    for (int rr = 0; rr < 4; ++rr) {
        int i = base + rr * 256 + (int)threadIdx.x;
        int o = -1, rank = 0;
        if (i < n) { o = off[i]; rank = atomicAdd(&lh[o], 1); }
        __syncthreads();
        if (threadIdx.x < 8) {
            int c = lh[threadIdx.x];
            gb[threadIdx.x] = c ? atomicAdd(&cursor[threadIdx.x], c) : 0;
        }
        __syncthreads();
        if (o >= 0) perm[gb[o] + rank] = i;
        __syncthreads();
        if (threadIdx.x < 8) lh[threadIdx.x] = 0;
        __syncthreads();
    }
}

// Unified grouped gather-GEMM. Out row i (i = perm[r] for gathered levels):
//   out[i][0:128] = concat(Aprev[parent[i]][0:CP], bf16(Askip[i][0:CS])) @ B_g
// with B_g given pre-transposed: BT[g][n][k], n<128, k<K, K = CP + CS.
template <int K, int CP, int CS, bool GATHER, bool OUT_BF16>
__global__ __launch_bounds__(256, 1) void gemm_k(
    const float* __restrict__ Askip, const __bf16* __restrict__ Aprev,
    const __bf16* __restrict__ BT, const int* __restrict__ perm,
    const int* __restrict__ parent, const int* __restrict__ ctr,
    int gs_off, int tb_off, void* __restrict__ outp, int M) {
    constexpr int LD = K + 8;  // +8 bf16 pad: row stride 16B-aligned, 4-dword bank rotate
    __shared__ __align__(16) __bf16 Al[64 * LD];
    __shared__ __align__(16) __bf16 Bl[128 * LD];
    __shared__ int orow[64];

    int g, r0, mcount;
    if constexpr (GATHER) {
        const int* tb = ctr + tb_off;
        int b = blockIdx.x;
        if (b >= tb[8]) return;
        g = 0;
        while (b >= tb[g + 1]) ++g;
        const int* gs = ctr + gs_off;
        r0 = gs[g] + (b - tb[g]) * 64;
        mcount = min(64, gs[g + 1] - r0);
    } else {
        g = 0;
        r0 = blockIdx.x * 64;
        mcount = min(64, M - r0);
    }

    const int tid = threadIdx.x;
    // ---- stage A (64 rows x K bf16), 4 threads per row ----
    {
        int j = tid >> 2, part = tid & 3;
        if (j < mcount) {
            int i, p = 0;
            if constexpr (GATHER) { i = perm[r0 + j]; p = parent[i]; }
            else { i = r0 + j; }
            if (part == 0) orow[j] = i;
            __bf16* arow = &Al[j * LD];
            if constexpr (CP > 0) {
                const uint4* src = (const uint4*)(Aprev + (size_t)p * CP) + part * (CP / 32);
                uint4* dst = (uint4*)arow + part * (CP / 32);
#pragma unroll
                for (int v = 0; v < CP / 32; ++v) dst[v] = src[v];
            }
            {
                const float4* src = (const float4*)(Askip + (size_t)i * CS) + part * (CS / 16);
                uint4* dst = (uint4*)(arow + CP + part * (CS / 4));
#pragma unroll
                for (int v = 0; v < CS / 16; v += 2) {
                    float4 f0 = src[v], f1 = src[v + 1];
                    uint4 w;
                    w.x = pack_bf16x2(f0.x, f0.y);
                    w.y = pack_bf16x2(f0.z, f0.w);
                    w.z = pack_bf16x2(f1.x, f1.y);
                    w.w = pack_bf16x2(f1.z, f1.w);
                    dst[v / 2] = w;
                }
            }
        }
    }
    // ---- stage B^T (128 rows x K bf16), 2 threads per row ----
    {
        int n = tid >> 1, half = tid & 1;
        const uint4* src = (const uint4*)(BT + ((size_t)g * 128 + n) * K) + half * (K / 16);
        uint4* dst = (uint4*)(Bl + n * LD) + half * (K / 16);
#pragma unroll
        for (int v = 0; v < K / 16; ++v) dst[v] = src[v];
    }
    __syncthreads();

    // ---- MFMA: wave wv does rows [16wv,16wv+16) x all 128 cols ----
    const int lane = tid & 63;
    const int wv = tid >> 6;
    const int m = lane & 15;
    const int q = lane >> 4;
    v4f acc[8] = {};
    const __bf16* arow = &Al[(wv * 16 + m) * LD + q * 8];
    const __bf16* brow = &Bl[m * LD + q * 8];
#pragma unroll
    for (int kk = 0; kk < K; kk += 32) {
        v8bf a = *(const v8bf*)(arow + kk);
#pragma unroll
        for (int t = 0; t < 8; ++t) {
            v8bf b = *(const v8bf*)(brow + t * 16 * LD + kk);
            acc[t] = __builtin_amdgcn_mfma_f32_16x16x32_bf16(a, b, acc[t], 0, 0, 0);
        }
    }

    // ---- epilogue: D[row=q*4+r][col=t*16+m] ----
#pragma unroll
    for (int r = 0; r < 4; ++r) {
        int j = wv * 16 + q * 4 + r;
        if (j < mcount) {
            size_t row = (size_t)orow[j] * 128;
            if constexpr (OUT_BF16) {
                __bf16* out = (__bf16*)outp;
#pragma unroll
                for (int t = 0; t < 8; ++t) out[row + t * 16 + m] = (__bf16)acc[t][r];
            } else {
                float* out = (float*)outp;
#pragma unroll
                for (int t = 0; t < 8; ++t) out[row + t * 16 + m] = acc[t][r];
            }
        }
    }
}

extern "C" void kernel_launch(void* const* d_in, const int* in_sizes, int n_in,
                              void* d_out, int out_size, void* d_ws, size_t ws_size,
                              hipStream_t stream) {
    const float* feats1 = (const float*)d_in[0];
    const float* feats2 = (const float*)d_in[1];
    const float* feats3 = (const float*)d_in[2];
    const int* parent1 = (const int*)d_in[3];
    const int* offset1 = (const int*)d_in[4];
    const int* parent2 = (const int*)d_in[5];
    const int* offset2 = (const int*)d_in[6];
    const float* W1 = (const float*)d_in[7];
    const float* W2 = (const float*)d_in[8];
    const float* W3 = (const float*)d_in[9];
    const float* T2 = (const float*)d_in[10];
    const float* T3 = (const float*)d_in[11];
    const int N1 = in_sizes[0] / 64;
    const int N2 = in_sizes[1] / 128;
    const int N3 = in_sizes[2] / 256;

    char* p = (char*)d_ws;
    auto take = [&](size_t bytes) {
        char* r = p;
        p += (bytes + 255) & ~(size_t)255;
        return r;
    };
    __bf16* y3b = (__bf16*)take((size_t)N3 * 128 * 2);
    __bf16* y2b = (__bf16*)take((size_t)N2 * 128 * 2);
    __bf16* W3T = (__bf16*)take((size_t)32768 * 2);
    __bf16* BT3 = (__bf16*)take((size_t)262144 * 2);
    __bf16* BT2 = (__bf16*)take((size_t)196608 * 2);
    int* perm1 = (int*)take((size_t)N1 * 4);
    int* perm2 = (int*)take((size_t)N2 * 4);
    int* ctr = (int*)take(68 * 4);

    hipMemsetAsync(ctr, 0, 16 * 4, stream);
    pack_weights<<<1920, 256, 0, stream>>>(W1, W2, W3, T2, T3, W3T, BT3, BT2);
    hist_kernel<<<512, 256, 0, stream>>>(offset1, N1, offset2, N2, ctr);
    scan_kernel<<<1, 64, 0, stream>>>(ctr);
    int nb1 = (N1 + 1023) / 1024, nb2 = (N2 + 1023) / 1024;
    scatter_kernel<<<nb1 + nb2, 256, 0, stream>>>(offset1, N1, nb1, offset2, N2, ctr, perm1,
                                                  perm2);
    // y3 = bf16(feats3 @ W3): K=256 all-skip, no gather
    gemm_k<256, 0, 256, false, true><<<(N3 + 63) / 64, 256, 0, stream>>>(
        feats3, nullptr, W3T, nullptr, nullptr, nullptr, 0, 0, y3b, N3);
    // y2 = tconv(y3,T3) + feats2@W2  (grouped, K=128+128)
    gemm_k<256, 128, 128, true, true><<<(N2 + 63) / 64 + 8, 256, 0, stream>>>(
        feats2, y3b, BT3, perm2, parent2, ctr, 41, 59, y2b, N2);
    // out = tconv(y2,T2) + feats1@W1  (grouped, K=128+64), fp32 out
    gemm_k<192, 128, 64, true, false><<<(N1 + 63) / 64 + 8, 256, 0, stream>>>(
        feats1, y2b, BT2, perm1, parent1, ctr, 32, 50, d_out, N1);
}

// Round 2
// 475.448 us; speedup vs baseline: 1.0166x; 1.0166x over previous
//
#include <hip/hip_runtime.h>

typedef __bf16 v8bf __attribute__((ext_vector_type(8)));
typedef float  v4f  __attribute__((ext_vector_type(4)));

__device__ inline unsigned pack_bf16x2(float x, float y) {
    unsigned short a = __builtin_bit_cast(unsigned short, (__bf16)x);
    unsigned short b = __builtin_bit_cast(unsigned short, (__bf16)y);
    return (unsigned)a | ((unsigned)b << 16);
}

// ---- counters layout in ws (int indices) ----
// [0..7]  cnt1   [8..15] cnt2   [16..23] cursor1  [24..31] cursor2
// [32..40] gs1   [41..49] gs2   [50..58] tb1      [59..67] tb2

// Fused weight-pack (blocks 0..1919) + offset histogram (blocks 1920..2431).
__global__ void pack_hist(const float* __restrict__ W1, const float* __restrict__ W2,
                          const float* __restrict__ W3, const float* __restrict__ T2,
                          const float* __restrict__ T3,
                          __bf16* __restrict__ W3T, __bf16* __restrict__ BT3,
                          __bf16* __restrict__ BT2,
                          const int* __restrict__ off1, int n1,
                          const int* __restrict__ off2, int n2, int* __restrict__ ctr) {
    if (blockIdx.x < 1920) {
        int idx = blockIdx.x * 256 + threadIdx.x;
        if (idx < 32768) {
            // W3T[d][c] = W3[c][d], d<128, c<256
            int c = idx & 255, d = idx >> 8;
            W3T[d * 256 + c] = (__bf16)W3[c * 128 + d];
        } else if (idx < 32768 + 262144) {
            // BT3[k][d][c]: c<128 -> T3[k][c][d], else W2[c-128][d]
            int t = idx - 32768;
            int c = t & 255, rest = t >> 8;
            int d = rest & 127, k = rest >> 7;
            float v = (c < 128) ? T3[((k * 128 + c) * 128) + d] : W2[(c - 128) * 128 + d];
            BT3[t] = (__bf16)v;
        } else if (idx < 32768 + 262144 + 196608) {
            // BT2[k][d][c]: c<128 -> T2[k][c][d], else W1[c-128][d]  (c<192)
            int t = idx - (32768 + 262144);
            int c = t % 192, rest = t / 192;
            int d = rest & 127, k = rest >> 7;
            float v = (c < 128) ? T2[((k * 128 + c) * 128) + d] : W1[(c - 128) * 128 + d];
            BT2[t] = (__bf16)v;
        }
    } else {
        __shared__ int lh[16];
        if (threadIdx.x < 16) lh[threadIdx.x] = 0;
        __syncthreads();
        int total = n1 + n2;
        for (int idx = (blockIdx.x - 1920) * 256 + threadIdx.x; idx < total; idx += 512 * 256) {
            if (idx < n1) atomicAdd(&lh[off1[idx]], 1);
            else          atomicAdd(&lh[8 + off2[idx - n1]], 1);
        }
        __syncthreads();
        if (threadIdx.x < 16) {
            int c = lh[threadIdx.x];
            if (c) atomicAdd(&ctr[threadIdx.x], c);
        }
    }
}

__global__ void scan_kernel(int* ctr) {
    if (threadIdx.x == 0 && blockIdx.x == 0) {
        int s = 0, tb = 0;
        for (int g = 0; g < 8; ++g) {
            ctr[32 + g] = s; ctr[16 + g] = s; ctr[50 + g] = tb;
            s += ctr[g]; tb += (ctr[g] + 63) >> 6;
        }
        ctr[32 + 8] = s; ctr[50 + 8] = tb;
        s = 0; tb = 0;
        for (int g = 0; g < 8; ++g) {
            ctr[41 + g] = s; ctr[24 + g] = s; ctr[59 + g] = tb;
            s += ctr[8 + g]; tb += (ctr[8 + g] + 63) >> 6;
        }
        ctr[41 + 8] = s; ctr[59 + 8] = tb;
    }
}

__global__ void scatter_kernel(const int* __restrict__ off1, int n1, int nb1,
                               const int* __restrict__ off2, int n2,
                               int* __restrict__ ctr, int* __restrict__ perm1,
                               int* __restrict__ perm2) {
    __shared__ int lh[8], gb[8];
    const int* off; int n, base; int* cursor; int* perm;
    if ((int)blockIdx.x < nb1) {
        off = off1; n = n1; base = blockIdx.x * 1024; cursor = ctr + 16; perm = perm1;
    } else {
        off = off2; n = n2; base = (blockIdx.x - nb1) * 1024; cursor = ctr + 24; perm = perm2;
    }
    if (threadIdx.x < 8) lh[threadIdx.x] = 0;
    __syncthreads();
    for (int rr = 0; rr < 4; ++rr) {
        int i = base + rr * 256 + (int)threadIdx.x;
        int o = -1, rank = 0;
        if (i < n) { o = off[i]; rank = atomicAdd(&lh[o], 1); }
        __syncthreads();
        if (threadIdx.x < 8) {
            int c = lh[threadIdx.x];
            gb[threadIdx.x] = c ? atomicAdd(&cursor[threadIdx.x], c) : 0;
        }
        __syncthreads();
        if (o >= 0) perm[gb[o] + rank] = i;
        __syncthreads();
        if (threadIdx.x < 8) lh[threadIdx.x] = 0;
        __syncthreads();
    }
}

// Grouped gather-GEMM, A-only LDS; each wave owns a 32-col slice with B
// fragments register-resident (B is small & L2-hot: one global read/block).
//   out[i][0:128] = concat(Aprev[parent[i]][0:CP], bf16(Askip[i][0:CS])) @ B_g
// BT[g][n][k] pre-transposed, n<128, k<K = CP+CS.
template <int K, int CP, int CS, bool GATHER, bool OUT_BF16, int MINW>
__global__ __launch_bounds__(256, MINW) void gemm_k(
    const float* __restrict__ Askip, const __bf16* __restrict__ Aprev,
    const __bf16* __restrict__ BT, const int* __restrict__ perm,
    const int* __restrict__ parent, const int* __restrict__ ctr,
    int gs_off, int tb_off, void* __restrict__ outp, int M) {
    constexpr int LD = K + 8;  // +8 bf16 pad: 4-dword bank rotation, <=2-way (free)
    __shared__ __align__(16) __bf16 Al[64 * LD];
    __shared__ int orow[64];

    int g, r0, mcount;
    if constexpr (GATHER) {
        const int* tb = ctr + tb_off;
        int b = blockIdx.x;
        if (b >= tb[8]) return;
        g = 0;
        while (b >= tb[g + 1]) ++g;
        const int* gs = ctr + gs_off;
        r0 = gs[g] + (b - tb[g]) * 64;
        mcount = min(64, gs[g + 1] - r0);
    } else {
        g = 0;
        r0 = blockIdx.x * 64;
        mcount = min(64, M - r0);
    }

    const int tid = threadIdx.x;
    const int lane = tid & 63;
    const int w = tid >> 6;   // wave = 32-col slice
    const int m = lane & 15;
    const int q = lane >> 4;

    // ---- preload B fragments to registers (issued early, overlaps A staging) ----
    constexpr int KS = K / 32;
    v8bf bfrag[2][KS];
    {
        const __bf16* bbase = BT + ((size_t)g * 128 + w * 32 + m) * K + q * 8;
#pragma unroll
        for (int t = 0; t < 2; ++t)
#pragma unroll
            for (int kk = 0; kk < KS; ++kk)
                bfrag[t][kk] = *(const v8bf*)(bbase + (size_t)t * 16 * K + kk * 32);
    }

    // ---- stage A (64 rows x K bf16) into LDS, 4 threads per row ----
    {
        int j = tid >> 2, part = tid & 3;
        if (j < mcount) {
            int i, p = 0;
            if constexpr (GATHER) { i = perm[r0 + j]; p = parent[i]; }
            else { i = r0 + j; }
            if (part == 0) orow[j] = i;
            __bf16* arow = &Al[j * LD];
            if constexpr (CP > 0) {
                const uint4* src = (const uint4*)(Aprev + (size_t)p * CP) + part * (CP / 32);
                uint4* dst = (uint4*)arow + part * (CP / 32);
#pragma unroll
                for (int v = 0; v < CP / 32; ++v) dst[v] = src[v];
            }
            {
                const float4* src = (const float4*)(Askip + (size_t)i * CS) + part * (CS / 16);
                uint4* dst = (uint4*)(arow + CP + part * (CS / 4));
#pragma unroll
                for (int v = 0; v < CS / 16; v += 2) {
                    float4 f0 = src[v], f1 = src[v + 1];
                    uint4 wd;
                    wd.x = pack_bf16x2(f0.x, f0.y);
                    wd.y = pack_bf16x2(f0.z, f0.w);
                    wd.z = pack_bf16x2(f1.x, f1.y);
                    wd.w = pack_bf16x2(f1.z, f1.w);
                    dst[v / 2] = wd;
                }
            }
        }
    }
    __syncthreads();

    // ---- MFMA: all 64 rows x this wave's 32 cols ----
    v4f acc[4][2] = {};
#pragma unroll
    for (int kk = 0; kk < KS; ++kk) {
#pragma unroll
        for (int rt = 0; rt < 4; ++rt) {
            v8bf a = *(const v8bf*)(&Al[(rt * 16 + m) * LD + q * 8 + kk * 32]);
            acc[rt][0] = __builtin_amdgcn_mfma_f32_16x16x32_bf16(a, bfrag[0][kk], acc[rt][0], 0, 0, 0);
            acc[rt][1] = __builtin_amdgcn_mfma_f32_16x16x32_bf16(a, bfrag[1][kk], acc[rt][1], 0, 0, 0);
        }
    }

    // ---- epilogue: D[row=rt*16+q*4+r][col=w*32+t*16+m] ----
#pragma unroll
    for (int rt = 0; rt < 4; ++rt) {
#pragma unroll
        for (int r = 0; r < 4; ++r) {
            int j = rt * 16 + q * 4 + r;
            if (j < mcount) {
                size_t row = (size_t)orow[j] * 128 + w * 32;
                if constexpr (OUT_BF16) {
                    __bf16* out = (__bf16*)outp;
                    out[row + m]      = (__bf16)acc[rt][0][r];
                    out[row + 16 + m] = (__bf16)acc[rt][1][r];
                } else {
                    float* out = (float*)outp;
                    out[row + m]      = acc[rt][0][r];
                    out[row + 16 + m] = acc[rt][1][r];
                }
            }
        }
    }
}

extern "C" void kernel_launch(void* const* d_in, const int* in_sizes, int n_in,
                              void* d_out, int out_size, void* d_ws, size_t ws_size,
                              hipStream_t stream) {
    const float* feats1 = (const float*)d_in[0];
    const float* feats2 = (const float*)d_in[1];
    const float* feats3 = (const float*)d_in[2];
    const int* parent1 = (const int*)d_in[3];
    const int* offset1 = (const int*)d_in[4];
    const int* parent2 = (const int*)d_in[5];
    const int* offset2 = (const int*)d_in[6];
    const float* W1 = (const float*)d_in[7];
    const float* W2 = (const float*)d_in[8];
    const float* W3 = (const float*)d_in[9];
    const float* T2 = (const float*)d_in[10];
    const float* T3 = (const float*)d_in[11];
    const int N1 = in_sizes[0] / 64;
    const int N2 = in_sizes[1] / 128;
    const int N3 = in_sizes[2] / 256;

    char* p = (char*)d_ws;
    auto take = [&](size_t bytes) {
        char* r = p;
        p += (bytes + 255) & ~(size_t)255;
        return r;
    };
    __bf16* y3b = (__bf16*)take((size_t)N3 * 128 * 2);
    __bf16* y2b = (__bf16*)take((size_t)N2 * 128 * 2);
    __bf16* W3T = (__bf16*)take((size_t)32768 * 2);
    __bf16* BT3 = (__bf16*)take((size_t)262144 * 2);
    __bf16* BT2 = (__bf16*)take((size_t)196608 * 2);
    int* perm1 = (int*)take((size_t)N1 * 4);
    int* perm2 = (int*)take((size_t)N2 * 4);
    int* ctr = (int*)take(68 * 4);

    hipMemsetAsync(ctr, 0, 16 * 4, stream);
    pack_hist<<<2432, 256, 0, stream>>>(W1, W2, W3, T2, T3, W3T, BT3, BT2,
                                        offset1, N1, offset2, N2, ctr);
    scan_kernel<<<1, 64, 0, stream>>>(ctr);
    int nb1 = (N1 + 1023) / 1024, nb2 = (N2 + 1023) / 1024;
    scatter_kernel<<<nb1 + nb2, 256, 0, stream>>>(offset1, N1, nb1, offset2, N2, ctr, perm1,
                                                  perm2);
    // y3 = bf16(feats3 @ W3): K=256 all-skip, no gather
    gemm_k<256, 0, 256, false, true, 3><<<(N3 + 63) / 64, 256, 0, stream>>>(
        feats3, nullptr, W3T, nullptr, nullptr, nullptr, 0, 0, y3b, N3);
    // y2 = tconv(y3,T3) + feats2@W2  (grouped, K=128+128)
    gemm_k<256, 128, 128, true, true, 3><<<(N2 + 63) / 64 + 8, 256, 0, stream>>>(
        feats2, y3b, BT3, perm2, parent2, ctr, 41, 59, y2b, N2);
    // out = tconv(y2,T2) + feats1@W1  (grouped, K=128+64), fp32 out
    gemm_k<192, 128, 64, true, false, 3><<<(N1 + 63) / 64 + 8, 256, 0, stream>>>(
        feats1, y2b, BT2, perm1, parent1, ctr, 32, 50, d_out, N1);
}